// Round 7
// baseline (430.677 us; speedup 1.0000x reference)
//
#include <hip/hip_runtime.h>
#include <math.h>

// Problem constants (from reference)
#define NDIM 64
#define NK   128
#define ALPHA_DP 1.0
#define TAU0 0.0
#define C0v  1.0
#define N0v  ((double)(NDIM + 2))
#define B0v  1.0

#define ITERS 2          // 256-point iterations per block (8 waves x 32 pts)
#define NSLOT 64         // ll partial-sum slots

typedef __attribute__((ext_vector_type(8))) short bf16x8;
typedef __attribute__((ext_vector_type(16))) float f32x16;

// ---------------- device math helpers ----------------
__device__ double digamma_d(double x) {
    double r = 0.0;
    while (x < 6.0) { r -= 1.0 / x; x += 1.0; }
    double inv = 1.0 / x, inv2 = inv * inv;
    double s = log(x) - 0.5 * inv
        - inv2 * (1.0/12.0 - inv2 * (1.0/120.0 - inv2 * (1.0/252.0
            - inv2 * (1.0/240.0 - inv2 * (1.0/132.0)))));
    return s + r;
}

__device__ inline unsigned pack_bf16_hi(float a, float b) {
    // dword = {bf16(a) lo16, bf16(b) hi16}; truncation split
    return (__float_as_uint(a) >> 16) | (__float_as_uint(b) & 0xffff0000u);
}

// fragment-major ushort index for W tables:
// feature f (0..127: x dims then y dims), cluster k.
// layout: [s=k>>5][kc=f>>4][g=(f>>3)&1][n=k&31][j=f&7]
__device__ inline int widx(int f, int k) {
    int kc = f >> 4, g = (f >> 3) & 1, j = f & 7, s = k >> 5, n = k & 31;
    return ((s * 8 + kc) * 2 + g) * 256 + n * 8 + j;
}

// ---------------- kernel 1: cluster prep (1 block, 128 threads) ----------------
// ws: scal[2] dbl | slots[64] dbl | constk[128] f32 | WhL (32KB) | WlL (32KB)
__global__ void prep_kernel(const float* __restrict__ nat_u,
                            const float* __restrict__ nat_v,
                            const float* __restrict__ nat_tau,
                            const float* __restrict__ nat_c,
                            const float* __restrict__ nat_n,
                            const float* __restrict__ nat_B,
                            double* __restrict__ scal,
                            double* __restrict__ slots,
                            float* __restrict__ constk,
                            unsigned short* __restrict__ Wh,
                            unsigned short* __restrict__ Wl) {
    const int k = threadIdx.x;          // cluster 0..127
    const int D = NDIM, K = NK;
    if (k < NSLOT) slots[k] = 0.0;      // zero ll partials (ws is poisoned)

    double u = (double)nat_u[k] + 1.0;
    double v = (double)nat_v[k] + 1.0;
    double c = (double)nat_c[k];
    double n = (double)nat_n[k] - (double)D - 2.0;

    double dg_u  = digamma_d(u);
    double dg_v  = digamma_d(v);
    double dg_uv = digamma_d(u + v);

    const double a0g = 0.5 * N0v;
    const double b0g = 0.5 * B0v;
    double sum_log_halfB = 0.0, sum_t2nb = 0.0, sum_nb = 0.0;
    double kl_g_d = 0.0, kl_n_d = 0.0;

    for (int d = 0; d < D; ++d) {
        double tau = (double)nat_tau[k * D + d] / c;
        double B   = (double)nat_B[k * D + d] - c * tau * tau;
        double nb  = n / B;
        float wx = (float)(tau * nb);          // coefficient on x_d   (feature d)
        float wy = (float)(-0.5 * nb);         // coefficient on y_d=x_d^2-1 (feature 64+d)
        unsigned bx = __float_as_uint(wx), by = __float_as_uint(wy);
        float hx = __uint_as_float(bx & 0xffff0000u);
        float hy = __uint_as_float(by & 0xffff0000u);
        Wh[widx(d, k)]      = (unsigned short)(bx >> 16);
        Wh[widx(64 + d, k)] = (unsigned short)(by >> 16);
        Wl[widx(d, k)]      = (unsigned short)(__float_as_uint(wx - hx) >> 16);
        Wl[widx(64 + d, k)] = (unsigned short)(__float_as_uint(wy - hy) >> 16);

        sum_log_halfB += log(0.5 * B);
        sum_t2nb += tau * tau * nb;
        sum_nb   += nb;
        double b1 = 0.5 * B;
        kl_g_d += a0g * (log(b1) - log(b0g)) + (0.5 * n) * (b0g - b1) / b1;
        kl_n_d += C0v * nb * (tau - TAU0) * (tau - TAU0);
    }

    double a1 = 0.5 * n;
    double e_log_det = (double)D * digamma_d(a1) - sum_log_halfB;

    __shared__ double sh[NK];
    sh[k] = dg_v - dg_uv;
    __syncthreads();
    double pre = 0.0;
    for (int j = 0; j < k; ++j) pre += sh[j];
    double e_log_pi = dg_u - dg_uv + pre;

    // logit = MFMA_acc + constk ; MFMA_acc = sum wx*x + sum wy*(x^2-1)
    const double LOG2PI = 1.8378770664093454836;
    double ck = e_log_pi + 0.5 * (e_log_det - (double)D * LOG2PI
                                  - sum_t2nb - (double)D / c - sum_nb);
    constk[k] = (float)ck;

    const double a0 = 1.0, b0 = ALPHA_DP;
    double kl_beta = lgamma(u + v) - lgamma(u) - lgamma(v)
        - (lgamma(a0 + b0) - lgamma(a0) - lgamma(b0))
        + (u - a0) * dg_u + (v - b0) * dg_v + (a0 + b0 - u - v) * dg_uv;

    double dga1 = digamma_d(a1);
    double kl_gamma = (double)D * ((a1 - a0g) * dga1 - lgamma(a1) + lgamma(a0g)) + kl_g_d;
    double kl_norm = 0.5 * ((double)D * (log(c / C0v) + C0v / c - 1.0) + kl_n_d);

    __syncthreads();
    sh[k] = kl_beta + kl_gamma + kl_norm;
    __syncthreads();
    if (k == 0) {
        double t = 0.0;
        for (int j = 0; j < K; ++j) t += sh[j];
        scal[1] = t;
        scal[0] = 0.0;
    }
}

// ---------------- kernel 2: barrier-free MFMA maha + in-wave softmax ----------------
// Block = 8 waves (512 thr); each wave independently handles 32 points x all 128
// clusters (4 strip-tiles of 32x32, split-bf16 hh+lh+hl). W staged once to LDS
// (fragment-major, sequential-sweep reads); A built in registers from global x
// (next iteration's x prefetched before the MFMA loop). Softmax entirely in-wave
// via shfl_xor; C-layout coalesced normal (write-back) stores — NT stores
// regressed 2x in r6 (sub-burst RMW amplification).
__global__ __launch_bounds__(512, 4) void maha_kernel(
    const float* __restrict__ x,
    const float* __restrict__ constk,
    const uint4* __restrict__ Wg,      // WhL then WlL, 64 KB fragment-major
    float* __restrict__ r,
    double* __restrict__ slots) {
    __shared__ __align__(16) uint4 W[4096];          // 64 KB
    const int tid = threadIdx.x;
#pragma unroll
    for (int i = 0; i < 8; ++i) W[i * 512 + tid] = Wg[i * 512 + tid];
    __syncthreads();                                  // only barrier in the kernel
    const unsigned short* Wh = (const unsigned short*)W;           // [0,32768)
    const unsigned short* Wl = (const unsigned short*)(W + 2048);  // [32768,65536)

    const int lane = tid & 63;
    const int w    = tid >> 6;              // 0..7
    const int g    = lane >> 5;
    const int m0   = lane & 31;

    float ck[4];
#pragma unroll
    for (int s = 0; s < 4; ++s) ck[s] = constk[s * 32 + m0];

    double dsum = 0.0;

    const long nbase = (long)blockIdx.x * (256 * ITERS) + w * 32;
    float xa[32];
    {   // prefetch iteration 0's x half-row
        const float* xr = x + (nbase + m0) * NDIM + g * 8;
#pragma unroll
        for (int t = 0; t < 4; ++t) {
            *(float4*)(xa + t * 8)     = *(const float4*)(xr + t * 16);
            *(float4*)(xa + t * 8 + 4) = *(const float4*)(xr + t * 16 + 4);
        }
    }

    for (int it = 0; it < ITERS; ++it) {
        const long n0 = nbase + it * 256;

        float xb[32];
        if (it + 1 < ITERS) {       // prefetch next iteration's x before compute
            const float* xr = x + (n0 + 256 + m0) * NDIM + g * 8;
#pragma unroll
            for (int t = 0; t < 4; ++t) {
                *(float4*)(xb + t * 8)     = *(const float4*)(xr + t * 16);
                *(float4*)(xb + t * 8 + 4) = *(const float4*)(xr + t * 16 + 4);
            }
        }

        f32x16 acc[4];
#pragma unroll
        for (int s = 0; s < 4; ++s)
#pragma unroll
            for (int i = 0; i < 16; ++i) acc[s][i] = 0.f;

        // ---- K loop: 8 chunks x 4 strips x (hh, lh, hl) ----
#pragma unroll
        for (int c = 0; c < 8; ++c) {
            float fe[8], lo[8];
#pragma unroll
            for (int e = 0; e < 8; ++e) {
                float xv = xa[((c & 3)) * 8 + e];
                fe[e] = (c < 4) ? xv : fmaf(xv, xv, -1.0f);   // x or y=x^2-1
            }
#pragma unroll
            for (int e = 0; e < 8; ++e) {
                float h = __uint_as_float(__float_as_uint(fe[e]) & 0xffff0000u);
                lo[e] = fe[e] - h;
            }
            union { bf16x8 v; unsigned d[4]; } ah, al;
#pragma unroll
            for (int q = 0; q < 4; ++q) {
                ah.d[q] = pack_bf16_hi(fe[2 * q], fe[2 * q + 1]);
                al.d[q] = pack_bf16_hi(lo[2 * q], lo[2 * q + 1]);
            }
            const int bidx = (c * 2 + g) * 256 + m0 * 8;      // ushort index
#pragma unroll
            for (int s = 0; s < 4; ++s) {
                bf16x8 bh = *(const bf16x8*)(Wh + bidx + s * 4096);
                bf16x8 bl = *(const bf16x8*)(Wl + bidx + s * 4096);
                acc[s] = __builtin_amdgcn_mfma_f32_32x32x16_bf16(ah.v, bh, acc[s], 0, 0, 0);
                acc[s] = __builtin_amdgcn_mfma_f32_32x32x16_bf16(al.v, bh, acc[s], 0, 0, 0);
                acc[s] = __builtin_amdgcn_mfma_f32_32x32x16_bf16(ah.v, bl, acc[s], 0, 0, 0);
            }
        }

        // ---- in-wave softmax per point; C/D: col=lane&31, row=(rg&3)+8*(rg>>2)+4*g ----
#pragma unroll
        for (int rg = 0; rg < 16; ++rg) {
            float l0 = acc[0][rg] + ck[0];
            float l1 = acc[1][rg] + ck[1];
            float l2 = acc[2][rg] + ck[2];
            float l3 = acc[3][rg] + ck[3];
            float M = fmaxf(fmaxf(l0, l1), fmaxf(l2, l3));
            M = fmaxf(M, __shfl_xor(M, 1, 64));
            M = fmaxf(M, __shfl_xor(M, 2, 64));
            M = fmaxf(M, __shfl_xor(M, 4, 64));
            M = fmaxf(M, __shfl_xor(M, 8, 64));
            M = fmaxf(M, __shfl_xor(M, 16, 64));
            float e0 = __expf(l0 - M), e1 = __expf(l1 - M);
            float e2 = __expf(l2 - M), e3 = __expf(l3 - M);
            float S = (e0 + e1) + (e2 + e3);
            S += __shfl_xor(S, 1, 64);
            S += __shfl_xor(S, 2, 64);
            S += __shfl_xor(S, 4, 64);
            S += __shfl_xor(S, 8, 64);
            S += __shfl_xor(S, 16, 64);
            const float inv = __builtin_amdgcn_rcpf(S);
            const int p = (rg & 3) + 8 * (rg >> 2) + 4 * g;
            float* rp = r + (n0 + p) * (long)NK + m0;
            rp[0]  = e0 * inv;
            rp[32] = e1 * inv;
            rp[64] = e2 * inv;
            rp[96] = e3 * inv;
            dsum += (double)(M + __logf(S));   // uniform within 32-lane half
        }

        if (it + 1 < ITERS) {
#pragma unroll
            for (int i = 0; i < 32; ++i) xa[i] = xb[i];
        }
    }

    // ---- ll: combine halves (each half's dsum covers its 16 pts/iter), 1 atomic/wave ----
    double d0  = __shfl(dsum, 0, 64);
    double d32 = __shfl(dsum, 32, 64);
    if (lane == 0) atomicAdd(&slots[((long)blockIdx.x * 8 + w) & (NSLOT - 1)], d0 + d32);
}

// ---------------- kernel 3: finalize scalar ----------------
__global__ void finalize_kernel(const double* __restrict__ scal,
                                const double* __restrict__ slots,
                                float* __restrict__ out) {
    double ll = 0.0;
    for (int i = 0; i < NSLOT; ++i) ll += slots[i];
    out[0] = (float)(scal[1] - ll);   // -elbo = kl_total - ll
}

extern "C" void kernel_launch(void* const* d_in, const int* in_sizes, int n_in,
                              void* d_out, int out_size, void* d_ws, size_t ws_size,
                              hipStream_t stream) {
    const float* x       = (const float*)d_in[0];
    const float* nat_u   = (const float*)d_in[1];
    const float* nat_v   = (const float*)d_in[2];
    const float* nat_tau = (const float*)d_in[3];
    const float* nat_c   = (const float*)d_in[4];
    const float* nat_n   = (const float*)d_in[5];
    const float* nat_B   = (const float*)d_in[6];

    const int N = in_sizes[0] / NDIM;
    float* out = (float*)d_out;

    // ws layout: scal 16B | slots 512B | constk 512B | W tables 64KB (16B-aligned)
    double* scal       = (double*)d_ws;
    double* slots      = (double*)((char*)d_ws + 16);
    float* constk      = (float*)((char*)d_ws + 16 + 512);
    unsigned short* Wh = (unsigned short*)((char*)d_ws + 1040);
    unsigned short* Wl = (unsigned short*)((char*)d_ws + 1040 + 32768);
    const uint4* Wg    = (const uint4*)((char*)d_ws + 1040);

    prep_kernel<<<1, NK, 0, stream>>>(nat_u, nat_v, nat_tau, nat_c, nat_n, nat_B,
                                      scal, slots, constk, Wh, Wl);
    maha_kernel<<<N / (256 * ITERS), 512, 0, stream>>>(x, constk, Wg, out, slots);
    finalize_kernel<<<1, 1, 0, stream>>>(scal, slots, out + (size_t)N * NK);
}

// Round 8
// 367.432 us; speedup vs baseline: 1.1721x; 1.1721x over previous
//
#include <hip/hip_runtime.h>
#include <math.h>

// Problem constants (from reference)
#define NDIM 64
#define NK   128
#define ALPHA_DP 1.0
#define TAU0 0.0
#define C0v  1.0
#define N0v  ((double)(NDIM + 2))
#define B0v  1.0

#define ITERS 4          // 128-point block-iterations (4 waves x 32 pts)
#define NSLOT 64         // ll partial-sum slots

typedef __attribute__((ext_vector_type(8))) short bf16x8;
typedef __attribute__((ext_vector_type(16))) float f32x16;

// ---------------- device math helpers ----------------
__device__ double digamma_d(double x) {
    double r = 0.0;
    while (x < 6.0) { r -= 1.0 / x; x += 1.0; }
    double inv = 1.0 / x, inv2 = inv * inv;
    double s = log(x) - 0.5 * inv
        - inv2 * (1.0/12.0 - inv2 * (1.0/120.0 - inv2 * (1.0/252.0
            - inv2 * (1.0/240.0 - inv2 * (1.0/132.0)))));
    return s + r;
}

__device__ inline unsigned pack_bf16_hi(float a, float b) {
    // dword = {bf16(a) lo16, bf16(b) hi16}; truncation split
    return (__float_as_uint(a) >> 16) | (__float_as_uint(b) & 0xffff0000u);
}

// fragment-major ushort index for W tables:
// feature f (0..127: x dims then y dims), cluster k.
// layout: [s=k>>5][kc=f>>4][g=(f>>3)&1][n=k&31][j=f&7]
__device__ inline int widx(int f, int k) {
    int kc = f >> 4, g = (f >> 3) & 1, j = f & 7, s = k >> 5, n = k & 31;
    return ((s * 8 + kc) * 2 + g) * 256 + n * 8 + j;
}

// ---------------- kernel 1: cluster prep (1 block, 128 threads) ----------------
// ws: scal[2] dbl | slots[64] dbl | ckperm[128] f32 | Wh (32KB) | Wl (32KB)
__global__ void prep_kernel(const float* __restrict__ nat_u,
                            const float* __restrict__ nat_v,
                            const float* __restrict__ nat_tau,
                            const float* __restrict__ nat_c,
                            const float* __restrict__ nat_n,
                            const float* __restrict__ nat_B,
                            double* __restrict__ scal,
                            double* __restrict__ slots,
                            float* __restrict__ ckperm,
                            unsigned short* __restrict__ Wh,
                            unsigned short* __restrict__ Wl) {
    const int k = threadIdx.x;          // cluster 0..127
    const int D = NDIM, K = NK;
    if (k < NSLOT) slots[k] = 0.0;      // zero ll partials (ws is poisoned)

    double u = (double)nat_u[k] + 1.0;
    double v = (double)nat_v[k] + 1.0;
    double c = (double)nat_c[k];
    double n = (double)nat_n[k] - (double)D - 2.0;

    double dg_u  = digamma_d(u);
    double dg_v  = digamma_d(v);
    double dg_uv = digamma_d(u + v);

    const double a0g = 0.5 * N0v;
    const double b0g = 0.5 * B0v;
    double sum_log_halfB = 0.0, sum_t2nb = 0.0, sum_nb = 0.0;
    double kl_g_d = 0.0, kl_n_d = 0.0;

    for (int d = 0; d < D; ++d) {
        double tau = (double)nat_tau[k * D + d] / c;
        double B   = (double)nat_B[k * D + d] - c * tau * tau;
        double nb  = n / B;
        float wx = (float)(tau * nb);          // coefficient on x_d   (feature d)
        float wy = (float)(-0.5 * nb);         // coefficient on y_d=x_d^2-1 (feature 64+d)
        unsigned bx = __float_as_uint(wx), by = __float_as_uint(wy);
        float hx = __uint_as_float(bx & 0xffff0000u);
        float hy = __uint_as_float(by & 0xffff0000u);
        Wh[widx(d, k)]      = (unsigned short)(bx >> 16);
        Wh[widx(64 + d, k)] = (unsigned short)(by >> 16);
        Wl[widx(d, k)]      = (unsigned short)(__float_as_uint(wx - hx) >> 16);
        Wl[widx(64 + d, k)] = (unsigned short)(__float_as_uint(wy - hy) >> 16);

        sum_log_halfB += log(0.5 * B);
        sum_t2nb += tau * tau * nb;
        sum_nb   += nb;
        double b1 = 0.5 * B;
        kl_g_d += a0g * (log(b1) - log(b0g)) + (0.5 * n) * (b0g - b1) / b1;
        kl_n_d += C0v * nb * (tau - TAU0) * (tau - TAU0);
    }

    double a1 = 0.5 * n;
    double e_log_det = (double)D * digamma_d(a1) - sum_log_halfB;

    __shared__ double sh[NK];
    sh[k] = dg_v - dg_uv;
    __syncthreads();
    double pre = 0.0;
    for (int j = 0; j < k; ++j) pre += sh[j];
    double e_log_pi = dg_u - dg_uv + pre;

    // logit = MFMA_acc + ck ; MFMA_acc = sum wx*x + sum wy*(x^2-1)
    const double LOG2PI = 1.8378770664093454836;
    double ck = e_log_pi + 0.5 * (e_log_det - (double)D * LOG2PI
                                  - sum_t2nb - (double)D / c - sum_nb);
    // permuted for the maha epilogue: ckperm[g][s][rg], k = s*32 + (rg&3)+8*(rg>>2)+4*g
    {
        int s = k >> 5, k5 = k & 31;
        int g = (k5 >> 2) & 1;
        int rg = (k5 & 3) + ((k5 >> 3) << 2);
        ckperm[g * 64 + s * 16 + rg] = (float)ck;
    }

    const double a0 = 1.0, b0 = ALPHA_DP;
    double kl_beta = lgamma(u + v) - lgamma(u) - lgamma(v)
        - (lgamma(a0 + b0) - lgamma(a0) - lgamma(b0))
        + (u - a0) * dg_u + (v - b0) * dg_v + (a0 + b0 - u - v) * dg_uv;

    double dga1 = digamma_d(a1);
    double kl_gamma = (double)D * ((a1 - a0g) * dga1 - lgamma(a1) + lgamma(a0g)) + kl_g_d;
    double kl_norm = 0.5 * ((double)D * (log(c / C0v) + C0v / c - 1.0) + kl_n_d);

    __syncthreads();
    sh[k] = kl_beta + kl_gamma + kl_norm;
    __syncthreads();
    if (k == 0) {
        double t = 0.0;
        for (int j = 0; j < K; ++j) t += sh[j];
        scal[1] = t;
        scal[0] = 0.0;
    }
}

// ---------------- kernel 2: swapped-operand MFMA maha + in-lane softmax ----------
// Block = 4 waves; each wave: 32 points x 128 clusters per iter, 4 k-strips.
// D = W * X^T  (A = W fragments from LDS/global, B = x fragments in registers;
// same per-lane fragment layouts as the X*W^T version — only operand order
// changes). C/D: col = point, row = k  ->  each lane holds 64 of its point's
// 128 logits; softmax = in-lane reduce + ONE shfl_xor(32) exchange.
// Wh (used 2x/chunk) lives in LDS (32 KB -> 3 blocks/CU); Wl (1x) from L2-hot
// global. launch_bounds(256,3): regs<=170, acc in AGPR, no spill.
__global__ __launch_bounds__(256, 3) void maha_kernel(
    const float* __restrict__ x,
    const float* __restrict__ ckperm_g,
    const uint4* __restrict__ WhG,     // 32 KB fragment-major
    const unsigned short* __restrict__ WlG,
    float* __restrict__ r,
    double* __restrict__ slots) {
    __shared__ __align__(16) uint4 W[2048];          // Wh, 32 KB
    __shared__ float ckl[128];
    const int tid = threadIdx.x;
#pragma unroll
    for (int i = 0; i < 8; ++i) W[i * 256 + tid] = WhG[i * 256 + tid];
    if (tid < 128) ckl[tid] = ckperm_g[tid];
    __syncthreads();                                  // only barrier in the kernel
    const unsigned short* Wh = (const unsigned short*)W;

    const int lane = tid & 63;
    const int w    = tid >> 6;              // 0..3
    const int g    = lane >> 5;
    const int m0   = lane & 31;

    double dsum = 0.0;

    for (int it = 0; it < ITERS; ++it) {
        const long n0 = (long)blockIdx.x * (128 * ITERS) + it * 128 + w * 32;

        // ---- load this lane's point-row half: dims {g*8+16t .. +8}, t=0..3 ----
        const float* xr = x + (n0 + m0) * NDIM + g * 8;
        float xa[32];
#pragma unroll
        for (int t = 0; t < 4; ++t) {
            *(float4*)(xa + t * 8)     = *(const float4*)(xr + t * 16);
            *(float4*)(xa + t * 8 + 4) = *(const float4*)(xr + t * 16 + 4);
        }

        f32x16 acc[4];
#pragma unroll
        for (int s = 0; s < 4; ++s)
#pragma unroll
            for (int i = 0; i < 16; ++i) acc[s][i] = 0.f;

        // ---- K loop: 8 chunks x 4 strips x (Wh*Xh, Wl*Xh, Wh*Xl) ----
#pragma unroll
        for (int c = 0; c < 8; ++c) {
            float fe[8], lo[8];
#pragma unroll
            for (int e = 0; e < 8; ++e) {
                float xv = xa[((c & 3)) * 8 + e];
                fe[e] = (c < 4) ? xv : fmaf(xv, xv, -1.0f);   // x or y=x^2-1
            }
#pragma unroll
            for (int e = 0; e < 8; ++e) {
                float h = __uint_as_float(__float_as_uint(fe[e]) & 0xffff0000u);
                lo[e] = fe[e] - h;
            }
            union { bf16x8 v; unsigned d[4]; } xh, xl;
#pragma unroll
            for (int q = 0; q < 4; ++q) {
                xh.d[q] = pack_bf16_hi(fe[2 * q], fe[2 * q + 1]);
                xl.d[q] = pack_bf16_hi(lo[2 * q], lo[2 * q + 1]);
            }
            const int bidx = (c * 2 + g) * 256 + m0 * 8;      // ushort index
#pragma unroll
            for (int s = 0; s < 4; ++s) {
                bf16x8 wh = *(const bf16x8*)(Wh + bidx + s * 4096);
                bf16x8 wl = *(const bf16x8*)(WlG + bidx + s * 4096);  // L2-hot
                acc[s] = __builtin_amdgcn_mfma_f32_32x32x16_bf16(wh, xh.v, acc[s], 0, 0, 0);
                acc[s] = __builtin_amdgcn_mfma_f32_32x32x16_bf16(wl, xh.v, acc[s], 0, 0, 0);
                acc[s] = __builtin_amdgcn_mfma_f32_32x32x16_bf16(wh, xl.v, acc[s], 0, 0, 0);
            }
        }

        // ---- in-lane softmax: lane holds k = s*32 + (rg&3)+8*(rg>>2)+4*g
        //      for its point (n0+m0); other 64 k's live in partner lane (xor 32).
        float mloc = -3.4e38f;
#pragma unroll
        for (int s = 0; s < 4; ++s) {
            const float* ckp = ckl + g * 64 + s * 16;
#pragma unroll
            for (int rg = 0; rg < 16; ++rg) {
                acc[s][rg] += ckp[rg];               // logits in acc
                mloc = fmaxf(mloc, acc[s][rg]);
            }
        }
        const float M = fmaxf(mloc, __shfl_xor(mloc, 32, 64));
        float sloc = 0.f;
#pragma unroll
        for (int s = 0; s < 4; ++s)
#pragma unroll
            for (int rg = 0; rg < 16; ++rg) {
                acc[s][rg] = __expf(acc[s][rg] - M);
                sloc += acc[s][rg];
            }
        const float S = sloc + __shfl_xor(sloc, 32, 64);
        const float inv = __builtin_amdgcn_rcpf(S);

        float* rp = r + (n0 + m0) * (long)NK + 4 * g;
#pragma unroll
        for (int s = 0; s < 4; ++s)
#pragma unroll
            for (int q = 0; q < 4; ++q) {
                float4 o = make_float4(acc[s][4 * q] * inv, acc[s][4 * q + 1] * inv,
                                       acc[s][4 * q + 2] * inv, acc[s][4 * q + 3] * inv);
                *(float4*)(rp + s * 32 + 8 * q) = o;
            }

        if (g == 0) dsum += (double)(M + __logf(S));   // one count per point
    }

    // ---- ll: reduce wave (g=1 lanes contributed 0), 1 atomic/wave ----
#pragma unroll
    for (int off = 32; off >= 1; off >>= 1) dsum += __shfl_xor(dsum, off, 64);
    if (lane == 0) atomicAdd(&slots[((long)blockIdx.x * 4 + w) & (NSLOT - 1)], dsum);
}

// ---------------- kernel 3: finalize scalar ----------------
__global__ void finalize_kernel(const double* __restrict__ scal,
                                const double* __restrict__ slots,
                                float* __restrict__ out) {
    double ll = 0.0;
    for (int i = 0; i < NSLOT; ++i) ll += slots[i];
    out[0] = (float)(scal[1] - ll);   // -elbo = kl_total - ll
}

extern "C" void kernel_launch(void* const* d_in, const int* in_sizes, int n_in,
                              void* d_out, int out_size, void* d_ws, size_t ws_size,
                              hipStream_t stream) {
    const float* x       = (const float*)d_in[0];
    const float* nat_u   = (const float*)d_in[1];
    const float* nat_v   = (const float*)d_in[2];
    const float* nat_tau = (const float*)d_in[3];
    const float* nat_c   = (const float*)d_in[4];
    const float* nat_n   = (const float*)d_in[5];
    const float* nat_B   = (const float*)d_in[6];

    const int N = in_sizes[0] / NDIM;
    float* out = (float*)d_out;

    // ws layout: scal 16B | slots 512B | ckperm 512B | Wh 32KB | Wl 32KB
    double* scal       = (double*)d_ws;
    double* slots      = (double*)((char*)d_ws + 16);
    float* ckperm      = (float*)((char*)d_ws + 16 + 512);
    unsigned short* Wh = (unsigned short*)((char*)d_ws + 1040);
    unsigned short* Wl = (unsigned short*)((char*)d_ws + 1040 + 32768);
    const uint4* WhG   = (const uint4*)((char*)d_ws + 1040);

    prep_kernel<<<1, NK, 0, stream>>>(nat_u, nat_v, nat_tau, nat_c, nat_n, nat_B,
                                      scal, slots, ckperm, Wh, Wl);
    maha_kernel<<<N / (128 * ITERS), 256, 0, stream>>>(x, ckperm, WhG, Wl, out, slots);
    finalize_kernel<<<1, 1, 0, stream>>>(scal, slots, out + (size_t)N * NK);
}